// Round 2
// baseline (695.648 us; speedup 1.0000x reference)
//
#include <hip/hip_runtime.h>

#define TT 140
#define BB 8192
#define HH 64
#define BPW 4   // batch elements per wave

typedef float v2f __attribute__((ext_vector_type(2)));

__device__ __forceinline__ float fast_tanh(float a) {
    // tanh(a) = 1 - 2/(e^{2a}+1);  e^{2a} = 2^(a * 2*log2(e))
    float e = __builtin_amdgcn_exp2f(a * 2.88539008178f);
    return 1.0f - 2.0f * __builtin_amdgcn_rcpf(e + 1.0f);
}

__global__ __launch_bounds__(64, 2)
void rnn_kernel(const float* __restrict__ x,
                const float* __restrict__ h_state,
                const float* __restrict__ W_ih0,
                const float* __restrict__ W_hh0,
                const float* __restrict__ b_ih0,
                const float* __restrict__ b_hh0,
                const float* __restrict__ W_ih1,
                const float* __restrict__ W_hh1,
                const float* __restrict__ b_ih1,
                const float* __restrict__ b_hh1,
                const float* __restrict__ W_out,
                const float* __restrict__ b_out,
                float* __restrict__ out)
{
    __shared__ __align__(16) float h0s[BPW][HH];
    __shared__ __align__(16) float h1s[BPW][HH];

    const int lane = threadIdx.x;      // 0..63, block = exactly one wave
    const int b0   = blockIdx.x * BPW; // first batch element of this wave

    // Per-lane weight rows (lane = output unit j). 3*32 v2f = 192 VGPRs.
    v2f w0[HH/2], w1i[HH/2], w1h[HH/2];
    #pragma unroll
    for (int k = 0; k < HH/2; ++k) {
        w0[k]  = *(const v2f*)(W_hh0 + lane*HH + 2*k);
        w1i[k] = *(const v2f*)(W_ih1 + lane*HH + 2*k);
        w1h[k] = *(const v2f*)(W_hh1 + lane*HH + 2*k);
    }
    const float wih0  = W_ih0[lane];
    const float bias0 = b_ih0[lane] + b_hh0[lane];
    const float bias1 = b_ih1[lane] + b_hh1[lane];
    const float wout  = W_out[lane];
    const float bout  = b_out[0];

    // init hidden state from h_state input ([2,B,H])
    #pragma unroll
    for (int b = 0; b < BPW; ++b) {
        h0s[b][lane] = h_state[(b0 + b)*HH + lane];
        h1s[b][lane] = h_state[(size_t)BB*HH + (b0 + b)*HH + lane];
    }
    __syncthreads();

    for (int t = 0; t < TT; ++t) {
        float xts[BPW];
        #pragma unroll
        for (int b = 0; b < BPW; ++b) xts[b] = x[(b0 + b)*TT + t];

        // ---- pass 1: layer-0 cell, h0 <- tanh(x*Wih0 + b + h0*Whh0^T) ----
        #pragma unroll
        for (int b = 0; b < BPW; ++b) {
            v2f acc0 = {0.f, 0.f}, acc1 = {0.f, 0.f};
            const v2f* h0p = (const v2f*)(&h0s[b][0]);  // broadcast reads
            #pragma unroll
            for (int k = 0; k < HH/2; k += 2) {
                acc0 = __builtin_elementwise_fma(w0[k],   h0p[k],   acc0);
                acc1 = __builtin_elementwise_fma(w0[k+1], h0p[k+1], acc1);
            }
            v2f accs = acc0 + acc1;
            float a  = accs.x + accs.y + bias0 + xts[b] * wih0;
            float hn = fast_tanh(a);
            h0s[b][lane] = hn;   // in-place: all reads of h0s[b] already issued (wave lockstep)
        }
        __syncthreads();  // h0n visible for pass 2

        float my_out = 0.f;
        // ---- pass 2: layer-1 cell + output projection ----
        #pragma unroll
        for (int b = 0; b < BPW; ++b) {
            v2f acc0 = {0.f, 0.f}, acc1 = {0.f, 0.f};
            const v2f* h0p = (const v2f*)(&h0s[b][0]);
            const v2f* h1p = (const v2f*)(&h1s[b][0]);
            #pragma unroll
            for (int k = 0; k < HH/2; ++k) {
                acc0 = __builtin_elementwise_fma(w1i[k], h0p[k], acc0);
                acc1 = __builtin_elementwise_fma(w1h[k], h1p[k], acc1);
            }
            v2f accs = acc0 + acc1;
            float a  = accs.x + accs.y + bias1;
            float hn = fast_tanh(a);
            h1s[b][lane] = hn;

            // out[b][t] = dot(h1n, W_out) + b_out  via 64-lane butterfly
            float p = hn * wout;
            #pragma unroll
            for (int off = 32; off > 0; off >>= 1)
                p += __shfl_xor(p, off, 64);
            if (lane == b) my_out = p + bout;
        }
        __syncthreads();  // h1n ordering for next step

        if (lane < BPW) out[(size_t)(b0 + lane)*TT + t] = my_out;
    }

    // h_final: [2,B,H] appended after out[B*T]
    const size_t OFF = (size_t)BB*TT;
    #pragma unroll
    for (int b = 0; b < BPW; ++b) {
        out[OFF + (size_t)(b0 + b)*HH + lane]                  = h0s[b][lane];
        out[OFF + (size_t)BB*HH + (size_t)(b0 + b)*HH + lane]  = h1s[b][lane];
    }
}

extern "C" void kernel_launch(void* const* d_in, const int* in_sizes, int n_in,
                              void* d_out, int out_size, void* d_ws, size_t ws_size,
                              hipStream_t stream) {
    const float* x      = (const float*)d_in[0];
    const float* hst    = (const float*)d_in[1];
    const float* W_ih0  = (const float*)d_in[2];
    const float* W_hh0  = (const float*)d_in[3];
    const float* b_ih0  = (const float*)d_in[4];
    const float* b_hh0  = (const float*)d_in[5];
    const float* W_ih1  = (const float*)d_in[6];
    const float* W_hh1  = (const float*)d_in[7];
    const float* b_ih1  = (const float*)d_in[8];
    const float* b_hh1  = (const float*)d_in[9];
    const float* W_out  = (const float*)d_in[10];
    const float* b_outp = (const float*)d_in[11];
    float* out = (float*)d_out;

    dim3 grid(BB / BPW);  // 2048 one-wave blocks
    dim3 block(64);
    rnn_kernel<<<grid, block, 0, stream>>>(x, hst, W_ih0, W_hh0, b_ih0, b_hh0,
                                           W_ih1, W_hh1, b_ih1, b_hh1,
                                           W_out, b_outp, out);
}

// Round 3
// 671.913 us; speedup vs baseline: 1.0353x; 1.0353x over previous
//
#include <hip/hip_runtime.h>

#define TT 140
#define BB 8192
#define HH 64
#define BPW 4   // batch elements per wave

typedef float v2f __attribute__((ext_vector_type(2)));
typedef float v4f __attribute__((ext_vector_type(4)));

// Packed FMA: acc.x += a.x*b.x, acc.y += a.y*b.y  (VOP3P, gfx90a+)
__device__ __forceinline__ void pk_fma(v2f& acc, v2f a, v2f b) {
    asm("v_pk_fma_f32 %0, %1, %2, %0" : "+v"(acc) : "v"(a), "v"(b));
}

__device__ __forceinline__ float fast_tanh(float a) {
    // tanh(a) = 1 - 2/(e^{2a}+1);  e^{2a} = 2^(a * 2*log2(e))
    float e = __builtin_amdgcn_exp2f(a * 2.88539008178f);
    return 1.0f - 2.0f * __builtin_amdgcn_rcpf(e + 1.0f);
}

__global__ __launch_bounds__(64, 2)
void rnn_kernel(const float* __restrict__ x,
                const float* __restrict__ h_state,
                const float* __restrict__ W_ih0,
                const float* __restrict__ W_hh0,
                const float* __restrict__ b_ih0,
                const float* __restrict__ b_hh0,
                const float* __restrict__ W_ih1,
                const float* __restrict__ W_hh1,
                const float* __restrict__ b_ih1,
                const float* __restrict__ b_hh1,
                const float* __restrict__ W_out,
                const float* __restrict__ b_out,
                float* __restrict__ out)
{
    // hs[b][0:64] = h0, hs[b][64:128] = h1  -> layer1 is one 128-long dot
    __shared__ __align__(16) float hs[BPW][2*HH];
    __shared__ __align__(16) float xs[TT][BPW];   // x staged, t-major

    const int lane = threadIdx.x;      // block = exactly one wave
    const int b0   = blockIdx.x * BPW;

    // ---- per-lane resident weights: lane = output unit j ----
    v2f w0[HH/2];   // W_hh0 row j            (64 floats)
    v2f w1[HH];     // [W_ih1 row j ; W_hh1 row j]  (128 floats)
    #pragma unroll
    for (int k = 0; k < HH/2; ++k) {
        w0[k]        = *(const v2f*)(W_hh0 + lane*HH + 2*k);
        w1[k]        = *(const v2f*)(W_ih1 + lane*HH + 2*k);
        w1[HH/2 + k] = *(const v2f*)(W_hh1 + lane*HH + 2*k);
    }
    // Pin: empty asm "writes" each value -> reload-remat is illegal, must stay in regs
    #pragma unroll
    for (int k = 0; k < HH/2; ++k) { asm volatile("" : "+v"(w0[k])); }
    #pragma unroll
    for (int k = 0; k < HH; ++k)   { asm volatile("" : "+v"(w1[k])); }

    const float wih0  = W_ih0[lane];
    const float bias0 = b_ih0[lane] + b_hh0[lane];
    const float bias1 = b_ih1[lane] + b_hh1[lane];
    const float wout  = W_out[lane];
    const float bout  = b_out[0];

    // ---- stage x[b0..b0+3][0..139] into LDS, t-major ----
    #pragma unroll
    for (int c = 0; c < (TT*BPW + 63) / 64; ++c) {
        int idx = c*64 + lane;
        if (idx < TT*BPW) {
            int t = idx >> 2, b = idx & 3;
            xs[t][b] = x[(size_t)(b0 + b)*TT + t];
        }
    }
    // ---- init hidden state ([2,B,H]) ----
    #pragma unroll
    for (int b = 0; b < BPW; ++b) {
        hs[b][lane]      = h_state[(size_t)(b0 + b)*HH + lane];
        hs[b][HH + lane] = h_state[(size_t)BB*HH + (size_t)(b0 + b)*HH + lane];
    }
    __syncthreads();  // one-time; block is a single wave so this is ~free

    for (int t = 0; t < TT; ++t) {
        v4f xt4 = *(const v4f*)(&xs[t][0]);   // 1 broadcast b128: x for all 4 batches
        float xtv[BPW] = {xt4.x, xt4.y, xt4.z, xt4.w};

        // ---- pass 1: h0 <- tanh(x*Wih0 + bias0 + Whh0 @ h0) ----
        #pragma unroll
        for (int b = 0; b < BPW; ++b) {
            const v4f* hp = (const v4f*)(&hs[b][0]);   // broadcast reads
            v2f a0 = {0.f,0.f}, a1 = {0.f,0.f}, a2 = {0.f,0.f}, a3 = {0.f,0.f};
            #pragma unroll
            for (int k = 0; k < HH/4; k += 2) {        // 16 ds_read_b128
                v4f h_a = hp[k];
                v4f h_b = hp[k+1];
                pk_fma(a0, w0[2*k],   __builtin_shufflevector(h_a, h_a, 0, 1));
                pk_fma(a1, w0[2*k+1], __builtin_shufflevector(h_a, h_a, 2, 3));
                pk_fma(a2, w0[2*k+2], __builtin_shufflevector(h_b, h_b, 0, 1));
                pk_fma(a3, w0[2*k+3], __builtin_shufflevector(h_b, h_b, 2, 3));
            }
            v2f s = (a0 + a1) + (a2 + a3);
            float acc = s.x + s.y + bias0 + xtv[b] * wih0;
            float hn = fast_tanh(acc);
            hs[b][lane] = hn;   // in-order DS within wave: all reads above precede this write
        }

        float my_out = 0.f;
        // ---- pass 2: h1 <- tanh(bias1 + [Wih1;Whh1] @ [h0n;h1]) + out projection ----
        #pragma unroll
        for (int b = 0; b < BPW; ++b) {
            const v4f* hp = (const v4f*)(&hs[b][0]);   // 128 floats: h0n then h1
            v2f a0 = {0.f,0.f}, a1 = {0.f,0.f}, a2 = {0.f,0.f}, a3 = {0.f,0.f};
            #pragma unroll
            for (int k = 0; k < (2*HH)/4; k += 2) {    // 32 ds_read_b128
                v4f h_a = hp[k];
                v4f h_b = hp[k+1];
                pk_fma(a0, w1[2*k],   __builtin_shufflevector(h_a, h_a, 0, 1));
                pk_fma(a1, w1[2*k+1], __builtin_shufflevector(h_a, h_a, 2, 3));
                pk_fma(a2, w1[2*k+2], __builtin_shufflevector(h_b, h_b, 0, 1));
                pk_fma(a3, w1[2*k+3], __builtin_shufflevector(h_b, h_b, 2, 3));
            }
            v2f s = (a0 + a1) + (a2 + a3);
            float acc = s.x + s.y + bias1;
            float hn = fast_tanh(acc);
            hs[b][HH + lane] = hn;

            // out[b][t] = dot(h1n, W_out) + b_out via 64-lane butterfly
            float p = hn * wout;
            #pragma unroll
            for (int off = 32; off > 0; off >>= 1)
                p += __shfl_xor(p, off, 64);
            if (lane == b) my_out = p + bout;
        }

        if (lane < BPW) out[(size_t)(b0 + lane)*TT + t] = my_out;
    }

    // ---- h_final: [2,B,H] appended after out[B*T] ----
    const size_t OFF = (size_t)BB*TT;
    #pragma unroll
    for (int b = 0; b < BPW; ++b) {
        out[OFF + (size_t)(b0 + b)*HH + lane]                 = hs[b][lane];
        out[OFF + (size_t)BB*HH + (size_t)(b0 + b)*HH + lane] = hs[b][HH + lane];
    }
}

extern "C" void kernel_launch(void* const* d_in, const int* in_sizes, int n_in,
                              void* d_out, int out_size, void* d_ws, size_t ws_size,
                              hipStream_t stream) {
    const float* x      = (const float*)d_in[0];
    const float* hst    = (const float*)d_in[1];
    const float* W_ih0  = (const float*)d_in[2];
    const float* W_hh0  = (const float*)d_in[3];
    const float* b_ih0  = (const float*)d_in[4];
    const float* b_hh0  = (const float*)d_in[5];
    const float* W_ih1  = (const float*)d_in[6];
    const float* W_hh1  = (const float*)d_in[7];
    const float* b_ih1  = (const float*)d_in[8];
    const float* b_hh1  = (const float*)d_in[9];
    const float* W_out  = (const float*)d_in[10];
    const float* b_outp = (const float*)d_in[11];
    float* out = (float*)d_out;

    dim3 grid(BB / BPW);  // 2048 one-wave blocks
    dim3 block(64);
    rnn_kernel<<<grid, block, 0, stream>>>(x, hst, W_ih0, W_hh0, b_ih0, b_hh0,
                                           W_ih1, W_hh1, b_ih1, b_hh1,
                                           W_out, b_outp, out);
}

// Round 5
// 367.418 us; speedup vs baseline: 1.8933x; 1.8287x over previous
//
#include <hip/hip_runtime.h>

#define TT 140
#define BB 8192
#define HH 64
#define BT 16   // batch tile per wave (MFMA N)
#define HS 68   // h-array stride in bf16 elems (136 B: 8B-aligned, odd dword count)

typedef __bf16 bf16x8 __attribute__((ext_vector_type(8)));
typedef __bf16 bf16x4 __attribute__((ext_vector_type(4)));
typedef float  f32x4  __attribute__((ext_vector_type(4)));

#define MFMA(a,b,c) __builtin_amdgcn_mfma_f32_16x16x32_bf16(a, b, c, 0, 0, 0)

__device__ __forceinline__ float fast_tanh(float a) {
    // tanh(a) = 1 - 2/(e^{2a}+1);  e^{2a} = 2^(a * 2*log2(e))
    float e = __builtin_amdgcn_exp2f(a * 2.88539008178f);
    return 1.0f - 2.0f * __builtin_amdgcn_rcpf(e + 1.0f);
}

// Load one B-fragment (8 bf16, 16 B) from an 8-B-aligned LDS address as 2x b64.
__device__ __forceinline__ bf16x8 load_bfrag(const __bf16* p) {
    bf16x4 a = *(const bf16x4*)(p);
    bf16x4 b = *(const bf16x4*)(p + 4);
    return __builtin_shufflevector(a, b, 0, 1, 2, 3, 4, 5, 6, 7);
}

// Split 8 fp32 weights into hi/lo bf16 fragments (W = hi + lo, RNE both).
__device__ __forceinline__ void cvt_frag(f32x4 wa, f32x4 wb, bf16x8& hi, bf16x8& lo) {
    #pragma unroll
    for (int j = 0; j < 8; ++j) {
        float f = (j < 4) ? wa[j] : wb[j - 4];
        __bf16 h = (__bf16)f;
        hi[j] = h;
        lo[j] = (__bf16)(f - (float)h);
    }
}

__global__ __launch_bounds__(64, 1)
void rnn_kernel(const float* __restrict__ x,
                const float* __restrict__ h_state,
                const float* __restrict__ W_ih0,
                const float* __restrict__ W_hh0,
                const float* __restrict__ b_ih0,
                const float* __restrict__ b_hh0,
                const float* __restrict__ W_ih1,
                const float* __restrict__ W_hh1,
                const float* __restrict__ b_ih1,
                const float* __restrict__ b_hh1,
                const float* __restrict__ W_out,
                const float* __restrict__ b_out,
                float* __restrict__ out)
{
    // h stored [batch][unit] bf16, split hi/lo; layer0 state and layer1 state
    __shared__ __bf16 h0hi[BT * HS], h0lo[BT * HS];
    __shared__ __bf16 h1hi[BT * HS], h1lo[BT * HS];
    __shared__ float  xs[TT * 17];    // x staged [t][b], stride 17 (bank-spread)
    __shared__ float  outs[TT * 17];  // y staged [t][b]

    const int lane = threadIdx.x;     // block = one wave
    const int col  = lane & 15;       // MFMA col: batch within tile / A-row m
    const int q    = lane >> 4;       // quad
    const int b0   = blockIdx.x * BT;

    // ---- A-fragments: weights, loaded ONCE, resident across all 140 steps ----
    // A[m=lane&15][k=quad*8+j] ; A0 = W_hh0 (K=64, 2 kt) ; A1 = [W_ih1 kt0-1 | W_hh1 kt2-3]
    bf16x8 A0h[4][2], A0l[4][2];
    bf16x8 A1h[4][4], A1l[4][4];
    #pragma unroll
    for (int mt = 0; mt < 4; ++mt) {
        #pragma unroll
        for (int kt = 0; kt < 2; ++kt) {
            const int off = (16 * mt + col) * HH + 32 * kt + 8 * q;
            const float* p0 = W_hh0 + off;
            cvt_frag(*(const f32x4*)p0, *(const f32x4*)(p0 + 4), A0h[mt][kt], A0l[mt][kt]);
            const float* p1 = W_ih1 + off;
            cvt_frag(*(const f32x4*)p1, *(const f32x4*)(p1 + 4), A1h[mt][kt], A1l[mt][kt]);
            const float* p2 = W_hh1 + off;
            cvt_frag(*(const f32x4*)p2, *(const f32x4*)(p2 + 4), A1h[mt][kt + 2], A1l[mt][kt + 2]);
        }
    }

    // ---- per-lane epilogue vectors, indexed [mt*4+r], j = 16*mt + 4*q + r ----
    float bias0v[16], bias1v[16], wih0v[16], woutv[16];
    #pragma unroll
    for (int mt = 0; mt < 4; ++mt) {
        #pragma unroll
        for (int r = 0; r < 4; ++r) {
            int j = 16 * mt + 4 * q + r;
            bias0v[4 * mt + r] = b_ih0[j] + b_hh0[j];
            bias1v[4 * mt + r] = b_ih1[j] + b_hh1[j];
            wih0v[4 * mt + r]  = W_ih0[j];
            woutv[4 * mt + r]  = W_out[j];
        }
    }
    const float bout = b_out[0];

    // ---- stage x[b0..b0+15][0..139] into LDS [t][b] ----
    for (int c = 0; c < (TT * BT + 63) / 64; ++c) {
        int i = c * 64 + lane;
        if (i < TT * BT) {
            int t = i >> 4, b = i & 15;
            xs[t * 17 + b] = x[(size_t)(b0 + b) * TT + t];
        }
    }

    // ---- init hidden state ([2,B,H]), split into hi/lo bf16; u = lane ----
    #pragma unroll
    for (int b = 0; b < BT; ++b) {
        float v0 = h_state[(size_t)(b0 + b) * HH + lane];
        float v1 = h_state[(size_t)BB * HH + (size_t)(b0 + b) * HH + lane];
        __bf16 c0 = (__bf16)v0;
        h0hi[b * HS + lane] = c0;
        h0lo[b * HS + lane] = (__bf16)(v0 - (float)c0);
        __bf16 c1 = (__bf16)v1;
        h1hi[b * HS + lane] = c1;
        h1lo[b * HS + lane] = (__bf16)(v1 - (float)c1);
    }
    __syncthreads();

    for (int t = 0; t < TT; ++t) {
        // prefetch: h1 fragments (h1 not written until layer-1 epilogue) + layer-0 h0 frags
        bf16x8 ch[4], cl[4];
        #pragma unroll
        for (int kt = 0; kt < 2; ++kt) {
            ch[kt + 2] = load_bfrag(&h1hi[col * HS + 32 * kt + 8 * q]);
            cl[kt + 2] = load_bfrag(&h1lo[col * HS + 32 * kt + 8 * q]);
        }
        bf16x8 bh[2], bl[2];
        #pragma unroll
        for (int kt = 0; kt < 2; ++kt) {
            bh[kt] = load_bfrag(&h0hi[col * HS + 32 * kt + 8 * q]);
            bl[kt] = load_bfrag(&h0lo[col * HS + 32 * kt + 8 * q]);
        }
        float xt = xs[t * 17 + col];  // 16 addrs x 4-lane broadcast: conflict-free

        // ---- layer 0: pre = W_hh0 @ h0 + x*Wih0 + bias; 4 independent 2-chains/tile ----
        #pragma unroll
        for (int mt = 0; mt < 4; ++mt) {
            f32x4 c0 = {0.f,0.f,0.f,0.f}, c1 = {0.f,0.f,0.f,0.f};
            f32x4 c2 = {0.f,0.f,0.f,0.f}, c3 = {0.f,0.f,0.f,0.f};
            #pragma unroll
            for (int kt = 0; kt < 2; ++kt) {
                c0 = MFMA(A0h[mt][kt], bh[kt], c0);
                c1 = MFMA(A0h[mt][kt], bl[kt], c1);
                c2 = MFMA(A0l[mt][kt], bh[kt], c2);
                c3 = MFMA(A0l[mt][kt], bl[kt], c3);
            }
            f32x4 a = (c0 + c1) + (c2 + c3);
            bf16x4 hi4, lo4;
            #pragma unroll
            for (int r = 0; r < 4; ++r) {
                float pre = a[r] + bias0v[4 * mt + r] + wih0v[4 * mt + r] * xt;
                float hn  = fast_tanh(pre);
                __bf16 h  = (__bf16)hn;
                hi4[r] = h;
                lo4[r] = (__bf16)(hn - (float)h);
            }
            *(bf16x4*)(&h0hi[col * HS + 16 * mt + 4 * q]) = hi4;
            *(bf16x4*)(&h0lo[col * HS + 16 * mt + 4 * q]) = lo4;
        }
        __syncthreads();  // h0n writes -> cross-lane reads below (RAW fence)

        // ---- layer 1: fragments of h0n ----
        #pragma unroll
        for (int kt = 0; kt < 2; ++kt) {
            ch[kt] = load_bfrag(&h0hi[col * HS + 32 * kt + 8 * q]);
            cl[kt] = load_bfrag(&h0lo[col * HS + 32 * kt + 8 * q]);
        }
        float p = 0.f;
        #pragma unroll
        for (int mt = 0; mt < 4; ++mt) {
            f32x4 c0 = {0.f,0.f,0.f,0.f}, c1 = {0.f,0.f,0.f,0.f};
            f32x4 c2 = {0.f,0.f,0.f,0.f}, c3 = {0.f,0.f,0.f,0.f};
            #pragma unroll
            for (int kt = 0; kt < 4; ++kt) {
                c0 = MFMA(A1h[mt][kt], ch[kt], c0);
                c1 = MFMA(A1h[mt][kt], cl[kt], c1);
                c2 = MFMA(A1l[mt][kt], ch[kt], c2);
                c3 = MFMA(A1l[mt][kt], cl[kt], c3);
            }
            f32x4 a = (c0 + c1) + (c2 + c3);
            bf16x4 hi4, lo4;
            #pragma unroll
            for (int r = 0; r < 4; ++r) {
                float pre = a[r] + bias1v[4 * mt + r];
                float hn  = fast_tanh(pre);
                p += hn * woutv[4 * mt + r];      // output projection partial (fp32 h)
                __bf16 h = (__bf16)hn;
                hi4[r] = h;
                lo4[r] = (__bf16)(hn - (float)h);
            }
            *(bf16x4*)(&h1hi[col * HS + 16 * mt + 4 * q]) = hi4;
            *(bf16x4*)(&h1lo[col * HS + 16 * mt + 4 * q]) = lo4;
        }
        // reduce partial over the 4 quads (lanes col, col+16, col+32, col+48)
        p += __shfl_xor(p, 16, 64);
        p += __shfl_xor(p, 32, 64);
        if (lane < 16) outs[t * 17 + lane] = p + bout;
        __syncthreads();  // h1 writes -> next-step reads (RAW fence)
    }

    // ---- epilogue: staged y -> global, coalesced per batch ----
    for (int b = 0; b < BT; ++b) {
        #pragma unroll
        for (int c = 0; c < 3; ++c) {
            int t = c * 64 + lane;
            if (t < TT) out[(size_t)(b0 + b) * TT + t] = outs[t * 17 + b];
        }
    }
    // ---- h_final: [2,B,H] appended after out[B*T]; u = lane ----
    const size_t OFF = (size_t)BB * TT;
    for (int b = 0; b < BT; ++b) {
        float v0 = (float)h0hi[b * HS + lane] + (float)h0lo[b * HS + lane];
        float v1 = (float)h1hi[b * HS + lane] + (float)h1lo[b * HS + lane];
        out[OFF + (size_t)(b0 + b) * HH + lane] = v0;
        out[OFF + (size_t)BB * HH + (size_t)(b0 + b) * HH + lane] = v1;
    }
}

extern "C" void kernel_launch(void* const* d_in, const int* in_sizes, int n_in,
                              void* d_out, int out_size, void* d_ws, size_t ws_size,
                              hipStream_t stream) {
    const float* x      = (const float*)d_in[0];
    const float* hst    = (const float*)d_in[1];
    const float* W_ih0  = (const float*)d_in[2];
    const float* W_hh0  = (const float*)d_in[3];
    const float* b_ih0  = (const float*)d_in[4];
    const float* b_hh0  = (const float*)d_in[5];
    const float* W_ih1  = (const float*)d_in[6];
    const float* W_hh1  = (const float*)d_in[7];
    const float* b_ih1  = (const float*)d_in[8];
    const float* b_hh1  = (const float*)d_in[9];
    const float* W_out  = (const float*)d_in[10];
    const float* b_outp = (const float*)d_in[11];
    float* out = (float*)d_out;

    dim3 grid(BB / BT);  // 512 one-wave blocks
    dim3 block(64);
    rnn_kernel<<<grid, block, 0, stream>>>(x, hst, W_ih0, W_hh0, b_ih0, b_hh0,
                                           W_ih1, W_hh1, b_ih1, b_hh1,
                                           W_out, b_outp, out);
}

// Round 6
// 206.534 us; speedup vs baseline: 3.3682x; 1.7790x over previous
//
#include <hip/hip_runtime.h>

#define TT 140
#define BB 8192
#define HH 64
#define BT 16   // batch tile per block (MFMA N)
#define HS 68   // h-array stride in bf16 elems (136 B, 8B-aligned)
#define WPB 4   // waves per block; wave w owns hidden units 16w..16w+15

typedef __bf16 bf16x8 __attribute__((ext_vector_type(8)));
typedef __bf16 bf16x4 __attribute__((ext_vector_type(4)));
typedef float  f32x4  __attribute__((ext_vector_type(4)));

#define MFMA(a,b,c) __builtin_amdgcn_mfma_f32_16x16x32_bf16(a, b, c, 0, 0, 0)

__device__ __forceinline__ float fast_tanh(float a) {
    float e = __builtin_amdgcn_exp2f(a * 2.88539008178f);
    return 1.0f - 2.0f * __builtin_amdgcn_rcpf(e + 1.0f);
}

__device__ __forceinline__ bf16x8 load_bfrag(const __bf16* p) {
    bf16x4 a = *(const bf16x4*)(p);
    bf16x4 b = *(const bf16x4*)(p + 4);
    return __builtin_shufflevector(a, b, 0, 1, 2, 3, 4, 5, 6, 7);
}

__device__ __forceinline__ void cvt_frag(f32x4 wa, f32x4 wb, bf16x8& hi, bf16x8& lo) {
    #pragma unroll
    for (int j = 0; j < 8; ++j) {
        float f = (j < 4) ? wa[j] : wb[j - 4];
        __bf16 h = (__bf16)f;
        hi[j] = h;
        lo[j] = (__bf16)(f - (float)h);
    }
}

__global__ __launch_bounds__(256, 2)
void rnn_kernel(const float* __restrict__ x,
                const float* __restrict__ h_state,
                const float* __restrict__ W_ih0,
                const float* __restrict__ W_hh0,
                const float* __restrict__ b_ih0,
                const float* __restrict__ b_hh0,
                const float* __restrict__ W_ih1,
                const float* __restrict__ W_hh1,
                const float* __restrict__ b_ih1,
                const float* __restrict__ b_hh1,
                const float* __restrict__ W_out,
                const float* __restrict__ b_out,
                float* __restrict__ out)
{
    __shared__ __bf16 h0hi[BT * HS], h0lo[BT * HS];
    __shared__ __bf16 h1hi[BT * HS], h1lo[BT * HS];
    __shared__ float  xs[TT * 17];     // x staged [t][b]
    __shared__ float  outs[TT * 17];   // y staged [t][b]
    __shared__ float  pp[WPB][20];     // per-wave output-projection partials

    const int tid  = threadIdx.x;
    const int w    = tid >> 6;        // wave id: owns units 16w..16w+15
    const int lane = tid & 63;
    const int col  = lane & 15;       // MFMA col (batch) / A-operand m
    const int q    = lane >> 4;       // quad
    const int b0   = blockIdx.x * BT;

    // ---- A-fragments for THIS wave's unit tile only ----
    bf16x8 A0h[2], A0l[2];            // W_hh0, kt=0..1
    bf16x8 A1h[4], A1l[4];            // [W_ih1 kt0-1 | W_hh1 kt2-3]
    #pragma unroll
    for (int kt = 0; kt < 2; ++kt) {
        const int off = (16 * w + col) * HH + 32 * kt + 8 * q;
        const float* p0 = W_hh0 + off;
        cvt_frag(*(const f32x4*)p0, *(const f32x4*)(p0 + 4), A0h[kt], A0l[kt]);
        const float* p1 = W_ih1 + off;
        cvt_frag(*(const f32x4*)p1, *(const f32x4*)(p1 + 4), A1h[kt], A1l[kt]);
        const float* p2 = W_hh1 + off;
        cvt_frag(*(const f32x4*)p2, *(const f32x4*)(p2 + 4), A1h[kt + 2], A1l[kt + 2]);
    }

    // ---- per-lane epilogue vectors for this wave's rows: j = 16w + 4q + r ----
    float bias0v[4], bias1v[4], wih0v[4], woutv[4];
    #pragma unroll
    for (int r = 0; r < 4; ++r) {
        int j = 16 * w + 4 * q + r;
        bias0v[r] = b_ih0[j] + b_hh0[j];
        bias1v[r] = b_ih1[j] + b_hh1[j];
        wih0v[r]  = W_ih0[j];
        woutv[r]  = W_out[j];
    }
    const float bout = b_out[0];

    // ---- stage x[b0..b0+15][0..139] into LDS [t][b] (256 threads) ----
    for (int c = 0; c < (TT * BT + 255) / 256; ++c) {
        int i = c * 256 + tid;
        if (i < TT * BT) {
            int t = i >> 4, b = i & 15;
            xs[t * 17 + b] = x[(size_t)(b0 + b) * TT + t];
        }
    }
    // ---- init hidden state ([2,B,H]), split hi/lo ----
    #pragma unroll
    for (int c = 0; c < (BT * HH) / 256; ++c) {
        int i = c * 256 + tid;
        int b = i >> 6, u = i & 63;
        float v0 = h_state[(size_t)(b0 + b) * HH + u];
        float v1 = h_state[(size_t)BB * HH + (size_t)(b0 + b) * HH + u];
        __bf16 c0 = (__bf16)v0;
        h0hi[b * HS + u] = c0;
        h0lo[b * HS + u] = (__bf16)(v0 - (float)c0);
        __bf16 c1 = (__bf16)v1;
        h1hi[b * HS + u] = c1;
        h1lo[b * HS + u] = (__bf16)(v1 - (float)c1);
    }
    __syncthreads();

    for (int t = 0; t < TT; ++t) {
        // prefetch h1 fragments (h1 untouched until layer-1 writes) + h0 frags
        bf16x8 ch[4], cl[4];
        #pragma unroll
        for (int kt = 0; kt < 2; ++kt) {
            ch[kt + 2] = load_bfrag(&h1hi[col * HS + 32 * kt + 8 * q]);
            cl[kt + 2] = load_bfrag(&h1lo[col * HS + 32 * kt + 8 * q]);
        }
        bf16x8 bh[2], bl[2];
        #pragma unroll
        for (int kt = 0; kt < 2; ++kt) {
            bh[kt] = load_bfrag(&h0hi[col * HS + 32 * kt + 8 * q]);
            bl[kt] = load_bfrag(&h0lo[col * HS + 32 * kt + 8 * q]);
        }
        float xt = xs[t * 17 + col];

        // ---- layer 0 (this wave's 16 units): 3 independent 2-chains ----
        {
            f32x4 c0 = {0.f,0.f,0.f,0.f}, c1 = {0.f,0.f,0.f,0.f}, c2 = {0.f,0.f,0.f,0.f};
            #pragma unroll
            for (int kt = 0; kt < 2; ++kt) {
                c0 = MFMA(A0h[kt], bh[kt], c0);   // hi*hi
                c1 = MFMA(A0h[kt], bl[kt], c1);   // hi*lo
                c2 = MFMA(A0l[kt], bh[kt], c2);   // lo*hi
            }
            f32x4 a = c0 + (c1 + c2);
            bf16x4 hi4, lo4;
            #pragma unroll
            for (int r = 0; r < 4; ++r) {
                float pre = a[r] + bias0v[r] + wih0v[r] * xt;
                float hn  = fast_tanh(pre);
                __bf16 h  = (__bf16)hn;
                hi4[r] = h;
                lo4[r] = (__bf16)(hn - (float)h);
            }
            *(bf16x4*)(&h0hi[col * HS + 16 * w + 4 * q]) = hi4;
            *(bf16x4*)(&h0lo[col * HS + 16 * w + 4 * q]) = lo4;
        }
        __syncthreads();  // h0n writes -> cross-wave reads (RAW)

        // ---- layer 1: load h0n frags, 3 independent 4-chains ----
        #pragma unroll
        for (int kt = 0; kt < 2; ++kt) {
            ch[kt] = load_bfrag(&h0hi[col * HS + 32 * kt + 8 * q]);
            cl[kt] = load_bfrag(&h0lo[col * HS + 32 * kt + 8 * q]);
        }
        float p = 0.f;
        {
            f32x4 c0 = {0.f,0.f,0.f,0.f}, c1 = {0.f,0.f,0.f,0.f}, c2 = {0.f,0.f,0.f,0.f};
            #pragma unroll
            for (int kt = 0; kt < 4; ++kt) {
                c0 = MFMA(A1h[kt], ch[kt], c0);
                c1 = MFMA(A1h[kt], cl[kt], c1);
                c2 = MFMA(A1l[kt], ch[kt], c2);
            }
            f32x4 a = c0 + (c1 + c2);
            bf16x4 hi4, lo4;
            #pragma unroll
            for (int r = 0; r < 4; ++r) {
                float pre = a[r] + bias1v[r];
                float hn  = fast_tanh(pre);
                p += hn * woutv[r];
                __bf16 h = (__bf16)hn;
                hi4[r] = h;
                lo4[r] = (__bf16)(hn - (float)h);
            }
            *(bf16x4*)(&h1hi[col * HS + 16 * w + 4 * q]) = hi4;
            *(bf16x4*)(&h1lo[col * HS + 16 * w + 4 * q]) = lo4;
        }
        // reduce p over quads -> this wave's partial for batch `col`
        p += __shfl_xor(p, 16, 64);
        p += __shfl_xor(p, 32, 64);
        if (lane < 16) pp[w][lane] = p;
        __syncthreads();  // h1 + pp writes -> next reads
        // wave 0 folds partials; safe: next pp writes happen only after the
        // layer-0 barrier of step t+1, which wave 0 reaches after this read.
        if (tid < 16)
            outs[t * 17 + tid] = pp[0][tid] + pp[1][tid] + pp[2][tid] + pp[3][tid] + bout;
    }
    __syncthreads();  // outs[last] visible to all

    // ---- epilogue: staged y -> global, coalesced in t; wave w does batches w,4+w,8+w,12+w
    for (int bq = 0; bq < 4; ++bq) {
        int b = 4 * bq + w;
        #pragma unroll
        for (int c = 0; c < 3; ++c) {
            int t = c * 64 + lane;
            if (t < TT) out[(size_t)(b0 + b) * TT + t] = outs[t * 17 + b];
        }
    }
    // ---- h_final: [2,B,H] appended after out[B*T] ----
    const size_t OFF = (size_t)BB * TT;
    #pragma unroll
    for (int c = 0; c < (BT * HH) / 256; ++c) {
        int i = c * 256 + tid;
        int b = i >> 6, u = i & 63;
        float v0 = (float)h0hi[b * HS + u] + (float)h0lo[b * HS + u];
        float v1 = (float)h1hi[b * HS + u] + (float)h1lo[b * HS + u];
        out[OFF + (size_t)(b0 + b) * HH + u] = v0;
        out[OFF + (size_t)BB * HH + (size_t)(b0 + b) * HH + u] = v1;
    }
}

extern "C" void kernel_launch(void* const* d_in, const int* in_sizes, int n_in,
                              void* d_out, int out_size, void* d_ws, size_t ws_size,
                              hipStream_t stream) {
    const float* x      = (const float*)d_in[0];
    const float* hst    = (const float*)d_in[1];
    const float* W_ih0  = (const float*)d_in[2];
    const float* W_hh0  = (const float*)d_in[3];
    const float* b_ih0  = (const float*)d_in[4];
    const float* b_hh0  = (const float*)d_in[5];
    const float* W_ih1  = (const float*)d_in[6];
    const float* W_hh1  = (const float*)d_in[7];
    const float* b_ih1  = (const float*)d_in[8];
    const float* b_hh1  = (const float*)d_in[9];
    const float* W_out  = (const float*)d_in[10];
    const float* b_outp = (const float*)d_in[11];
    float* out = (float*)d_out;

    dim3 grid(BB / BT);   // 512 blocks x 4 waves = 2048 waves (8/CU)
    dim3 block(256);
    rnn_kernel<<<grid, block, 0, stream>>>(x, hst, W_ih0, W_hh0, b_ih0, b_hh0,
                                           W_ih1, W_hh1, b_ih1, b_hh1,
                                           W_out, b_outp, out);
}

// Round 7
// 194.688 us; speedup vs baseline: 3.5731x; 1.0608x over previous
//
#include <hip/hip_runtime.h>

#define TT 140
#define BB 8192
#define HH 64
#define BT 16   // batch tile per block (MFMA N)
#define HS 68   // h-array stride in bf16 elems (136 B, 8B-aligned)
#define FP ((TT - 1) & 1)   // parity of final step (=1)

typedef __bf16 bf16x8 __attribute__((ext_vector_type(8)));
typedef __bf16 bf16x4 __attribute__((ext_vector_type(4)));
typedef float  f32x4  __attribute__((ext_vector_type(4)));

#define MFMA(a,b,c) __builtin_amdgcn_mfma_f32_16x16x32_bf16(a, b, c, 0, 0, 0)

__device__ __forceinline__ float fast_tanh(float a) {
    float e = __builtin_amdgcn_exp2f(a * 2.88539008178f);
    return 1.0f - 2.0f * __builtin_amdgcn_rcpf(e + 1.0f);
}

__device__ __forceinline__ bf16x8 load_bfrag(const __bf16* p) {
    bf16x4 a = *(const bf16x4*)(p);
    bf16x4 b = *(const bf16x4*)(p + 4);
    return __builtin_shufflevector(a, b, 0, 1, 2, 3, 4, 5, 6, 7);
}

__device__ __forceinline__ void cvt_frag(const float* p, bf16x8& hi, bf16x8& lo) {
    f32x4 wa = *(const f32x4*)p;
    f32x4 wb = *(const f32x4*)(p + 4);
    #pragma unroll
    for (int j = 0; j < 8; ++j) {
        float f = (j < 4) ? wa[j] : wb[j - 4];
        __bf16 h = (__bf16)f;
        hi[j] = h;
        lo[j] = (__bf16)(f - (float)h);
    }
}

// Wave-specialized pipeline: waves 0-3 = layer0 (step p), waves 4-7 = layer1
// (step p-1). One barrier per phase. All state double-buffered by step parity.
__global__ __launch_bounds__(512, 4)
void rnn_kernel(const float* __restrict__ x,
                const float* __restrict__ h_state,
                const float* __restrict__ W_ih0,
                const float* __restrict__ W_hh0,
                const float* __restrict__ b_ih0,
                const float* __restrict__ b_hh0,
                const float* __restrict__ W_ih1,
                const float* __restrict__ W_hh1,
                const float* __restrict__ b_ih1,
                const float* __restrict__ b_hh1,
                const float* __restrict__ W_out,
                const float* __restrict__ b_out,
                float* __restrict__ out)
{
    __shared__ __bf16 h0hi[2][BT * HS], h0lo[2][BT * HS];
    __shared__ __bf16 h1hi[2][BT * HS], h1lo[2][BT * HS];
    __shared__ float  xs[TT * 17];     // x staged [t][b]
    __shared__ float  outs[TT * 17];   // y staged [t][b]
    __shared__ float  pp[2][4][20];    // projection partials, dbuf by step parity

    const int tid  = threadIdx.x;
    const int w    = tid >> 6;        // 0..7
    const int grp  = w >> 2;          // 0 = layer0 group, 1 = layer1 group
    const int wl   = w & 3;           // unit-tile within layer (units 16*wl..)
    const int lane = tid & 63;
    const int col  = lane & 15;       // MFMA col (batch) / A-operand m
    const int q    = lane >> 4;       // quad
    const int b0   = blockIdx.x * BT;

    // ---- A-fragments, overlaid across groups to cap static VGPR liveness ----
    // grp0: AF[0..1]=Whh0_hi(kt), AF[2..3]=Whh0_lo(kt)
    // grp1: AF[0..3]=A1_hi(kt: ih1 kt0-1, hh1 kt2-3), AF[4..7]=A1_lo(kt)
    bf16x8 AF[8];
    if (grp == 0) {
        #pragma unroll
        for (int kt = 0; kt < 2; ++kt) {
            const int off = (16 * wl + col) * HH + 32 * kt + 8 * q;
            cvt_frag(W_hh0 + off, AF[kt], AF[2 + kt]);
            AF[4 + kt] = AF[kt]; AF[6 + kt] = AF[2 + kt];  // keep defined
        }
    } else {
        #pragma unroll
        for (int kt = 0; kt < 2; ++kt) {
            const int off = (16 * wl + col) * HH + 32 * kt + 8 * q;
            cvt_frag(W_ih1 + off, AF[kt],     AF[4 + kt]);
            cvt_frag(W_hh1 + off, AF[2 + kt], AF[6 + kt]);
        }
    }
    // epilogue scalars, overlaid: grp0: e0=bias0, e1=Wih0 ; grp1: e0=bias1, e1=Wout
    float e0[4], e1[4];
    #pragma unroll
    for (int r = 0; r < 4; ++r) {
        int j = 16 * wl + 4 * q + r;
        if (grp == 0) { e0[r] = b_ih0[j] + b_hh0[j]; e1[r] = W_ih0[j]; }
        else          { e0[r] = b_ih1[j] + b_hh1[j]; e1[r] = W_out[j]; }
    }
    const float bout = b_out[0];

    // ---- stage x[b0..b0+15][0..139] into LDS [t][b] (512 threads) ----
    for (int c = 0; c < (TT * BT + 511) / 512; ++c) {
        int i = c * 512 + tid;
        if (i < TT * BT) {
            int t = i >> 4, b = i & 15;
            xs[t * 17 + b] = x[(size_t)(b0 + b) * TT + t];
        }
    }
    // ---- init hidden state ([2,B,H]) into parity-1 buffers (step "-1") ----
    #pragma unroll
    for (int c = 0; c < (BT * HH) / 512; ++c) {
        int i = c * 512 + tid;
        int b = i >> 6, u = i & 63;
        float v0 = h_state[(size_t)(b0 + b) * HH + u];
        float v1 = h_state[(size_t)BB * HH + (size_t)(b0 + b) * HH + u];
        __bf16 c0 = (__bf16)v0;
        h0hi[1][b * HS + u] = c0;
        h0lo[1][b * HS + u] = (__bf16)(v0 - (float)c0);
        __bf16 c1 = (__bf16)v1;
        h1hi[1][b * HS + u] = c1;
        h1lo[1][b * HS + u] = (__bf16)(v1 - (float)c1);
    }
    __syncthreads();

    // ---- pipelined phase loop: p=0..TT+1 ----
    for (int p = 0; p <= TT + 1; ++p) {
        if (grp == 0) {
            if (p < TT) {
                // layer0 step p: read h0(p-1) parity (p+1)&1, write h0(p) parity p&1
                const int rb = (p + 1) & 1, wb = p & 1;
                bf16x8 HFh[2], HFl[2];
                #pragma unroll
                for (int kt = 0; kt < 2; ++kt) {
                    HFh[kt] = load_bfrag(&h0hi[rb][col * HS + 32 * kt + 8 * q]);
                    HFl[kt] = load_bfrag(&h0lo[rb][col * HS + 32 * kt + 8 * q]);
                }
                float xt = xs[p * 17 + col];
                f32x4 c0 = {0.f,0.f,0.f,0.f}, c1 = {0.f,0.f,0.f,0.f}, c2 = {0.f,0.f,0.f,0.f};
                #pragma unroll
                for (int kt = 0; kt < 2; ++kt) {
                    c0 = MFMA(AF[kt],     HFh[kt], c0);   // hi*hi
                    c1 = MFMA(AF[kt],     HFl[kt], c1);   // hi*lo
                    c2 = MFMA(AF[2 + kt], HFh[kt], c2);   // lo*hi
                }
                f32x4 a = c0 + (c1 + c2);
                bf16x4 hi4, lo4;
                #pragma unroll
                for (int r = 0; r < 4; ++r) {
                    float pre = a[r] + e0[r] + e1[r] * xt;
                    float hn  = fast_tanh(pre);
                    __bf16 h  = (__bf16)hn;
                    hi4[r] = h;
                    lo4[r] = (__bf16)(hn - (float)h);
                }
                *(bf16x4*)(&h0hi[wb][col * HS + 16 * wl + 4 * q]) = hi4;
                *(bf16x4*)(&h0lo[wb][col * HS + 16 * wl + 4 * q]) = lo4;
            }
            // folder (wave 0): fold step p-2 partials written at phase p-1 (parity p&1)
            if (w == 0 && p >= 2 && lane < 16) {
                const int s = p - 2, par = p & 1;
                outs[s * 17 + lane] = pp[par][0][lane] + pp[par][1][lane]
                                    + pp[par][2][lane] + pp[par][3][lane] + bout;
            }
        } else {
            if (p >= 1 && p <= TT) {
                // layer1 step s=p-1: read h0n(s) parity s&1 (written by grp0 last
                // phase), h1(s-1) parity (s+1)&1; write h1(s) parity s&1
                const int s   = p - 1;
                const int rb0 = s & 1, rb1 = (s + 1) & 1, wb1 = s & 1;
                bf16x8 HFh[4], HFl[4];
                #pragma unroll
                for (int kt = 0; kt < 2; ++kt) {
                    HFh[kt]     = load_bfrag(&h0hi[rb0][col * HS + 32 * kt + 8 * q]);
                    HFl[kt]     = load_bfrag(&h0lo[rb0][col * HS + 32 * kt + 8 * q]);
                    HFh[2 + kt] = load_bfrag(&h1hi[rb1][col * HS + 32 * kt + 8 * q]);
                    HFl[2 + kt] = load_bfrag(&h1lo[rb1][col * HS + 32 * kt + 8 * q]);
                }
                f32x4 c0 = {0.f,0.f,0.f,0.f}, c1 = {0.f,0.f,0.f,0.f}, c2 = {0.f,0.f,0.f,0.f};
                #pragma unroll
                for (int kt = 0; kt < 4; ++kt) {
                    c0 = MFMA(AF[kt],     HFh[kt], c0);
                    c1 = MFMA(AF[kt],     HFl[kt], c1);
                    c2 = MFMA(AF[4 + kt], HFh[kt], c2);
                }
                f32x4 a = c0 + (c1 + c2);
                float pr = 0.f;
                bf16x4 hi4, lo4;
                #pragma unroll
                for (int r = 0; r < 4; ++r) {
                    float pre = a[r] + e0[r];
                    float hn  = fast_tanh(pre);
                    pr += hn * e1[r];
                    __bf16 h = (__bf16)hn;
                    hi4[r] = h;
                    lo4[r] = (__bf16)(hn - (float)h);
                }
                *(bf16x4*)(&h1hi[wb1][col * HS + 16 * wl + 4 * q]) = hi4;
                *(bf16x4*)(&h1lo[wb1][col * HS + 16 * wl + 4 * q]) = lo4;
                pr += __shfl_xor(pr, 16, 64);
                pr += __shfl_xor(pr, 32, 64);
                if (lane < 16) pp[s & 1][wl][lane] = pr;
            }
        }
        __syncthreads();
    }

    // ---- epilogue: staged y -> global; wave w does batches w and 8+w ----
    #pragma unroll
    for (int bq = 0; bq < 2; ++bq) {
        int b = 8 * bq + w;
        #pragma unroll
        for (int c = 0; c < 3; ++c) {
            int t = c * 64 + lane;
            if (t < TT) out[(size_t)(b0 + b) * TT + t] = outs[t * 17 + b];
        }
    }
    // ---- h_final: [2,B,H] appended after out[B*T]; final parity FP ----
    const size_t OFF = (size_t)BB * TT;
    #pragma unroll
    for (int c = 0; c < (BT * HH) / 512; ++c) {
        int i = c * 512 + tid;
        int b = i >> 6, u = i & 63;
        float v0 = (float)h0hi[FP][b * HS + u] + (float)h0lo[FP][b * HS + u];
        float v1 = (float)h1hi[FP][b * HS + u] + (float)h1lo[FP][b * HS + u];
        out[OFF + (size_t)(b0 + b) * HH + u] = v0;
        out[OFF + (size_t)BB * HH + (size_t)(b0 + b) * HH + u] = v1;
    }
}

extern "C" void kernel_launch(void* const* d_in, const int* in_sizes, int n_in,
                              void* d_out, int out_size, void* d_ws, size_t ws_size,
                              hipStream_t stream) {
    const float* x      = (const float*)d_in[0];
    const float* hst    = (const float*)d_in[1];
    const float* W_ih0  = (const float*)d_in[2];
    const float* W_hh0  = (const float*)d_in[3];
    const float* b_ih0  = (const float*)d_in[4];
    const float* b_hh0  = (const float*)d_in[5];
    const float* W_ih1  = (const float*)d_in[6];
    const float* W_hh1  = (const float*)d_in[7];
    const float* b_ih1  = (const float*)d_in[8];
    const float* b_hh1  = (const float*)d_in[9];
    const float* W_out  = (const float*)d_in[10];
    const float* b_outp = (const float*)d_in[11];
    float* out = (float*)d_out;

    dim3 grid(BB / BT);   // 512 blocks x 8 waves = 4096 waves (16/CU at 2 blk/CU)
    dim3 block(512);
    rnn_kernel<<<grid, block, 0, stream>>>(x, hst, W_ih0, W_hh0, b_ih0, b_hh0,
                                           W_ih1, W_hh1, b_ih1, b_hh1,
                                           W_out, b_outp, out);
}